// Round 1
// baseline (1153.497 us; speedup 1.0000x reference)
//
#include <hip/hip_runtime.h>
#include <math.h>

// Problem constants
#define BATCH 16384
#define NWIN_PER 32
#define DIM 64
#define KCB 512
#define NWIN (BATCH * NWIN_PER)      // 524288 windows
#define ZQN (NWIN * DIM)             // 33554432 elements
#define TILE_K 128                   // codebook rows per LDS tile

// ---------------------------------------------------------------------------
// Kernel 1: per-window argmin over codebook.
// Distance surrogate: ||cb_k||^2 - 2*<ze_w, cb_k>  (||ze_w||^2 constant per row)
// One thread = one window (64 floats in VGPRs). Codebook staged in LDS in
// 128-row tiles (32 KiB); all inner-loop LDS reads are wave-uniform ->
// broadcast, conflict-free. Writes index as float into d_out[0..NWIN).
// ---------------------------------------------------------------------------
__global__ __launch_bounds__(256) void vq_argmin_kernel(
    const float* __restrict__ ze, const float* __restrict__ cb,
    float* __restrict__ out_idx)
{
    __shared__ float4 cb_s[TILE_K * 16];   // 128 rows x 64 floats = 32 KiB
    __shared__ float  norm_s[TILE_K];

    const int t = threadIdx.x;
    const long w = (long)blockIdx.x * 256 + t;

    // Load this thread's window vector (64 consecutive floats) into registers.
    float4 zv[16];
    const float4* zp = (const float4*)(ze + w * DIM);
#pragma unroll
    for (int i = 0; i < 16; ++i) zv[i] = zp[i];

    float best = 3.4e38f;
    int bidx = 0;

    for (int tile = 0; tile < KCB / TILE_K; ++tile) {
        __syncthreads();  // protect LDS from previous tile's readers
        // Stage tile: 2048 float4, 256 threads x 8 coalesced float4 each.
        const float4* cp = (const float4*)(cb + (long)tile * TILE_K * DIM);
#pragma unroll
        for (int i = 0; i < 8; ++i) cb_s[t + i * 256] = cp[t + i * 256];
        __syncthreads();

        // Precompute row norms for this tile.
        if (t < TILE_K) {
            float s = 0.f;
#pragma unroll
            for (int i = 0; i < 16; ++i) {
                float4 v = cb_s[t * 16 + i];
                s += v.x * v.x + v.y * v.y + v.z * v.z + v.w * v.w;
            }
            norm_s[t] = s;
        }
        __syncthreads();

        for (int k = 0; k < TILE_K; ++k) {
            float acc = 0.f;
#pragma unroll
            for (int i = 0; i < 16; ++i) {
                float4 c = cb_s[k * 16 + i];
                acc += zv[i].x * c.x + zv[i].y * c.y + zv[i].z * c.z + zv[i].w * c.w;
            }
            float score = norm_s[k] - 2.f * acc;
            if (score < best) { best = score; bidx = tile * TILE_K + k; }  // first-min tiebreak (matches jnp.argmin)
        }
    }
    out_idx[w] = (float)bidx;
}

// ---------------------------------------------------------------------------
// Kernel 2: gather zq = codebook[idx], accumulate sum((zq-ze)^2), and build
// the code-usage histogram (LDS-local then global atomics).
// One thread = one window.
// ---------------------------------------------------------------------------
__global__ __launch_bounds__(256) void vq_gather_kernel(
    const float* __restrict__ ze, const float* __restrict__ cb,
    const float* __restrict__ idxf, float* __restrict__ zq,
    int* __restrict__ counts, float* __restrict__ lossAcc)
{
    __shared__ int   hist[KCB];
    __shared__ float partial[4];

    const int t = threadIdx.x;
    hist[t] = 0;
    hist[t + 256] = 0;
    __syncthreads();

    const long w = (long)blockIdx.x * 256 + t;
    const int idx = (int)idxf[w];
    atomicAdd(&hist[idx], 1);

    const float4* cp = (const float4*)(cb + (long)idx * DIM);
    const float4* zp = (const float4*)(ze + w * DIM);
    float4*       qp = (float4*)(zq + w * DIM);

    float lsum = 0.f;
#pragma unroll
    for (int i = 0; i < 16; ++i) {
        float4 c = cp[i];
        float4 z = zp[i];
        float dx = c.x - z.x, dy = c.y - z.y, dz = c.z - z.z, dw = c.w - z.w;
        lsum += dx * dx + dy * dy + dz * dz + dw * dw;
        qp[i] = c;
    }

    // wave64 reduce
#pragma unroll
    for (int off = 32; off > 0; off >>= 1) lsum += __shfl_down(lsum, off, 64);
    if ((t & 63) == 0) partial[t >> 6] = lsum;
    __syncthreads();
    if (t == 0) {
        float s = partial[0] + partial[1] + partial[2] + partial[3];
        atomicAdd(lossAcc, s);
    }

    // flush histogram (skip zero bins to cut atomic traffic)
    int h0 = hist[t];
    int h1 = hist[t + 256];
    if (h0) atomicAdd(&counts[t], h0);
    if (h1) atomicAdd(&counts[t + 256], h1);
}

// ---------------------------------------------------------------------------
// Kernel 3: entropy from counts + final scalars.
// outs[0]=vq_e_loss, outs[1]=vq_commit_loss (same forward value), outs[2]=entropy
// ---------------------------------------------------------------------------
__global__ __launch_bounds__(512) void vq_finalize_kernel(
    const int* __restrict__ counts, const float* __restrict__ lossAcc,
    float* __restrict__ outs)
{
    __shared__ float partial[8];
    const int t = threadIdx.x;

    float p = (float)counts[t] * 0.1f;
    float term = p * logf(p + 1e-10f);
#pragma unroll
    for (int off = 32; off > 0; off >>= 1) term += __shfl_down(term, off, 64);
    if ((t & 63) == 0) partial[t >> 6] = term;
    __syncthreads();
    if (t == 0) {
        float e = 0.f;
#pragma unroll
        for (int i = 0; i < 8; ++i) e += partial[i];
        float loss = lossAcc[0] / (float)ZQN;
        outs[0] = loss;
        outs[1] = loss;
        outs[2] = e;
    }
}

extern "C" void kernel_launch(void* const* d_in, const int* in_sizes, int n_in,
                              void* d_out, int out_size, void* d_ws, size_t ws_size,
                              hipStream_t stream) {
    const float* ze = (const float*)d_in[0];   // [16384, 2048]
    const float* cb = (const float*)d_in[1];   // [512, 64]
    float* out = (float*)d_out;

    // d_out layout: [idx: NWIN | zq: ZQN | vq_e | vq_commit | entropy]
    float* out_idx = out;
    float* out_zq  = out + NWIN;
    float* out_scl = out + NWIN + (long)ZQN;

    // workspace: counts[512] (int) + lossAcc (float). Re-poisoned each call ->
    // zero it every launch (memset node is graph-capturable).
    int*   counts  = (int*)d_ws;
    float* lossAcc = (float*)((char*)d_ws + KCB * sizeof(int));
    hipMemsetAsync(d_ws, 0, KCB * sizeof(int) + sizeof(float), stream);

    vq_argmin_kernel<<<NWIN / 256, 256, 0, stream>>>(ze, cb, out_idx);
    vq_gather_kernel<<<NWIN / 256, 256, 0, stream>>>(ze, cb, out_idx, out_zq, counts, lossAcc);
    vq_finalize_kernel<<<1, 512, 0, stream>>>(counts, lossAcc, out_scl);
}

// Round 2
// 291.619 us; speedup vs baseline: 3.9555x; 3.9555x over previous
//
#include <hip/hip_runtime.h>
#include <math.h>

// Problem constants
#define DIM 64
#define KCB 512
#define NWIN 524288              // 16384 * 32 windows
#define ZQN (NWIN * DIM)         // 33554432
#define WPB 256                  // windows per block
#define NBLK (NWIN / WPB)        // 2048 blocks

typedef __attribute__((ext_vector_type(8))) short bf16x8;  // 8 bf16 = 4 VGPRs
typedef __attribute__((ext_vector_type(4))) float f32x4;

__device__ __forceinline__ unsigned bfbits(float f) { return __float_as_uint(f) >> 16; }

// pack 8 fp32 -> 8 bf16 (truncation; precision budget is enormous here)
__device__ __forceinline__ int4 pack8(float4 a, float4 b) {
    int4 r;
    r.x = (int)(bfbits(a.x) | (__float_as_uint(a.y) & 0xffff0000u));
    r.y = (int)(bfbits(a.z) | (__float_as_uint(a.w) & 0xffff0000u));
    r.z = (int)(bfbits(b.x) | (__float_as_uint(b.y) & 0xffff0000u));
    r.w = (int)(bfbits(b.z) | (__float_as_uint(b.w) & 0xffff0000u));
    return r;
}

// ---------------------------------------------------------------------------
// Fused: MFMA distance GEMM + argmin + index write + zq gather + loss + hist.
//   dist surrogate score = 0.5*||c_n||^2 - <z,c_n>; argmin via fminf with the
//   code index packed into the low 9 mantissa bits (2^-14 relative clearing
//   error, far under tolerance). d^2 = ||z||^2 + 2*score reproduces the loss
//   without re-reading ze.
// MFMA 16x16x32 bf16: A[m=lane&15][k=quad*8+j], B[k=quad*8+j][n=lane&15],
// D: col(n)=lane&15, row(m)=quad*4+reg  (layouts HW-verified per guide §3).
// ---------------------------------------------------------------------------
__global__ __launch_bounds__(256, 4) void vq_fused_kernel(
    const float* __restrict__ ze, const float* __restrict__ cb,
    float* __restrict__ out_idx, float* __restrict__ zq,
    int* __restrict__ counts, float* __restrict__ lossAcc)
{
    __shared__ int4  bfr[2048];     // 32 KiB: B frags, [chunk16][h2][lane64], lane-linear
    __shared__ float norm_s[KCB];   // 2 KiB codebook row norms
    __shared__ int   idx_s[WPB];    // 1 KiB per-window argmin
    __shared__ int   hist_s[KCB];   // 2 KiB histogram
    __shared__ float lpart[4];

    const int t    = threadIdx.x;
    const int lane = t & 63;
    const int wv   = t >> 6;        // wave 0..3
    const int q    = lane >> 4;     // quad
    const int l15  = lane & 15;
    const long blk = blockIdx.x;

    hist_s[t] = 0; hist_s[t + 256] = 0;

    // ---- codebook row norms (L2-hot, 128 KiB)
    {
        const float4* c4 = (const float4*)cb;
        for (int rr = t; rr < KCB; rr += 256) {
            float s = 0.f;
#pragma unroll
            for (int i = 0; i < 16; ++i) {
                float4 v = c4[rr * 16 + i];
                s += v.x * v.x + v.y * v.y + v.z * v.z + v.w * v.w;
            }
            norm_s[rr] = s;
        }
    }

    // ---- A fragments: global -> VGPR (bf16), plus window norms via shfl
    bf16x8 afrag[4][2];
    float  znorm[4];
    {
        const float4* z4 = (const float4*)(ze + blk * WPB * DIM);
#pragma unroll
        for (int tt = 0; tt < 4; ++tt) {
            float part = 0.f;
            int m = wv * 64 + tt * 16 + l15;     // window within block
#pragma unroll
            for (int h = 0; h < 2; ++h) {
                int off = m * 16 + h * 8 + q * 2;   // float4 units: k = h*32+q*8
                float4 a0 = z4[off], a1 = z4[off + 1];
                part += a0.x*a0.x + a0.y*a0.y + a0.z*a0.z + a0.w*a0.w
                      + a1.x*a1.x + a1.y*a1.y + a1.z*a1.z + a1.w*a1.w;
                int4 p = pack8(a0, a1);
                afrag[tt][h] = __builtin_bit_cast(bf16x8, p);
            }
            part += __shfl_xor(part, 16, 64);    // sum over quads (k-groups)
            part += __shfl_xor(part, 32, 64);
            znorm[tt] = part;
        }
    }

    float best[4][4];
#pragma unroll
    for (int tt = 0; tt < 4; ++tt)
#pragma unroll
        for (int r = 0; r < 4; ++r) best[tt][r] = __uint_as_float(0x7e000000u);

    // ---- N in two halves of 256 codes (32 KiB B-frag LDS each)
    for (int half = 0; half < 2; ++half) {
        __syncthreads();   // prior readers done (and norms visible on first pass)
        // stage 2048 B fragments, 8 per thread, in MFMA fragment order
#pragma unroll
        for (int i = 0; i < 8; ++i) {
            int f = i * 256 + t;
            int L = f & 63, rest = f >> 6, h = rest & 1, c = rest >> 1;
            int n = half * 256 + c * 16 + (L & 15);
            int k = h * 32 + (L >> 4) * 8;
            const float4* s4 = (const float4*)(cb + n * DIM + k);
            bfr[(c * 2 + h) * 64 + L] = pack8(s4[0], s4[1]);
        }
        __syncthreads();

        for (int c = 0; c < 16; ++c) {
            bf16x8 b0 = __builtin_bit_cast(bf16x8, bfr[(c * 2 + 0) * 64 + lane]);
            bf16x8 b1 = __builtin_bit_cast(bf16x8, bfr[(c * 2 + 1) * 64 + lane]);
            int   n   = half * 256 + c * 16 + l15;
            float nrm = norm_s[n];
#pragma unroll
            for (int tt = 0; tt < 4; ++tt) {
                f32x4 acc = {0.f, 0.f, 0.f, 0.f};
                acc = __builtin_amdgcn_mfma_f32_16x16x32_bf16(afrag[tt][0], b0, acc, 0, 0, 0);
                acc = __builtin_amdgcn_mfma_f32_16x16x32_bf16(afrag[tt][1], b1, acc, 0, 0, 0);
#pragma unroll
                for (int r = 0; r < 4; ++r) {
                    float sc = fmaf(nrm, 0.5f, -acc[r]);
                    unsigned bb = (__float_as_uint(sc) & ~511u) | (unsigned)n;
                    best[tt][r] = fminf(best[tt][r], __uint_as_float(bb));
                }
            }
        }
    }

    // ---- min across the 16 lanes of each quad (n-direction)
#pragma unroll
    for (int tt = 0; tt < 4; ++tt)
#pragma unroll
        for (int r = 0; r < 4; ++r) {
            float v = best[tt][r];
            v = fminf(v, __shfl_xor(v, 1, 64));
            v = fminf(v, __shfl_xor(v, 2, 64));
            v = fminf(v, __shfl_xor(v, 4, 64));
            v = fminf(v, __shfl_xor(v, 8, 64));
            best[tt][r] = v;
        }

    // ---- epilogue: quad q holds windows m = 4q + r; lane with l15==4q+r writes
    float lsum = 0.f;
    int  r_act = l15 - q * 4;
    bool act   = (r_act >= 0) && (r_act < 4);
#pragma unroll
    for (int tt = 0; tt < 4; ++tt) {
        if (act) {
            unsigned bb = __float_as_uint(best[tt][r_act]);
            int   n  = (int)(bb & 511u);
            float sc = __uint_as_float(bb & ~511u);
            float d2 = fmaf(2.f, sc, znorm[tt]);   // ||z||^2 + 2*score = dist^2
            int w_loc = wv * 64 + tt * 16 + l15;
            idx_s[w_loc] = n;
            out_idx[blk * WPB + w_loc] = (float)n;
            lsum += d2;
        }
    }
#pragma unroll
    for (int off = 32; off; off >>= 1) lsum += __shfl_down(lsum, off, 64);
    if (lane == 0) lpart[wv] = lsum;
    __syncthreads();

    // histogram: one window per thread
    atomicAdd(&hist_s[idx_s[t]], 1);
    if (t == 0) atomicAdd(lossAcc, lpart[0] + lpart[1] + lpart[2] + lpart[3]);

    // gather zq: 16 windows per iter, fully coalesced 4 KiB stores
    {
        const float4* c4  = (const float4*)cb;
        float4*       zq4 = (float4*)zq;
        const long base = blk * WPB * 16;   // float4 units
#pragma unroll
        for (int it = 0; it < 16; ++it) {
            int w_loc = it * 16 + (t >> 4);
            int n = idx_s[w_loc];
            zq4[base + (long)w_loc * 16 + (t & 15)] = c4[n * 16 + (t & 15)];
        }
    }
    __syncthreads();
    int h0 = hist_s[t], h1 = hist_s[t + 256];
    if (h0) atomicAdd(&counts[t], h0);
    if (h1) atomicAdd(&counts[t + 256], h1);
}

// ---------------------------------------------------------------------------
// Finalize: entropy from counts + loss scalars
// ---------------------------------------------------------------------------
__global__ __launch_bounds__(512) void vq_finalize_kernel(
    const int* __restrict__ counts, const float* __restrict__ lossAcc,
    float* __restrict__ outs)
{
    __shared__ float partial[8];
    const int t = threadIdx.x;

    float p = (float)counts[t] * 0.1f;
    float term = p * logf(p + 1e-10f);
#pragma unroll
    for (int off = 32; off; off >>= 1) term += __shfl_down(term, off, 64);
    if ((t & 63) == 0) partial[t >> 6] = term;
    __syncthreads();
    if (t == 0) {
        float e = 0.f;
#pragma unroll
        for (int i = 0; i < 8; ++i) e += partial[i];
        float loss = lossAcc[0] / (float)ZQN;
        outs[0] = loss;
        outs[1] = loss;
        outs[2] = e;
    }
}

extern "C" void kernel_launch(void* const* d_in, const int* in_sizes, int n_in,
                              void* d_out, int out_size, void* d_ws, size_t ws_size,
                              hipStream_t stream) {
    const float* ze = (const float*)d_in[0];   // [16384, 2048] fp32
    const float* cb = (const float*)d_in[1];   // [512, 64] fp32
    float* out = (float*)d_out;

    // d_out layout: [idx: NWIN | zq: ZQN | vq_e | vq_commit | entropy]
    float* out_idx = out;
    float* out_zq  = out + NWIN;
    float* out_scl = out + NWIN + (long)ZQN;

    int*   counts  = (int*)d_ws;
    float* lossAcc = (float*)((char*)d_ws + KCB * sizeof(int));
    hipMemsetAsync(d_ws, 0, KCB * sizeof(int) + sizeof(float), stream);

    vq_fused_kernel<<<NBLK, 256, 0, stream>>>(ze, cb, out_idx, out_zq, counts, lossAcc);
    vq_finalize_kernel<<<1, KCB, 0, stream>>>(counts, lossAcc, out_scl);
}

// Round 3
// 285.243 us; speedup vs baseline: 4.0439x; 1.0224x over previous
//
#include <hip/hip_runtime.h>
#include <math.h>

// Problem constants
#define DIM 64
#define KCB 512
#define NWIN 524288              // 16384 * 32 windows
#define ZQN (NWIN * DIM)         // 33554432
#define WPT 256                  // windows per tile
#define TPB 4                    // tiles per block
#define NBLK (NWIN / (WPT * TPB))  // 512 blocks = 2 per CU

typedef __attribute__((ext_vector_type(8))) short bf16x8;  // 8 bf16 = 4 VGPRs
typedef __attribute__((ext_vector_type(4))) float f32x4;

__device__ __forceinline__ unsigned bfbits(float f) { return __float_as_uint(f) >> 16; }

// pack 8 fp32 -> 8 bf16 (truncation; tolerance budget is enormous)
__device__ __forceinline__ int4 pack8(float4 a, float4 b) {
    int4 r;
    r.x = (int)(bfbits(a.x) | (__float_as_uint(a.y) & 0xffff0000u));
    r.y = (int)(bfbits(a.z) | (__float_as_uint(a.w) & 0xffff0000u));
    r.z = (int)(bfbits(b.x) | (__float_as_uint(b.y) & 0xffff0000u));
    r.w = (int)(bfbits(b.z) | (__float_as_uint(b.w) & 0xffff0000u));
    return r;
}

// ---------------------------------------------------------------------------
// Streaming fused kernel: stage all 512 codes as MFMA B-frags in LDS once,
// then loop 4 window-tiles with register-prefetched A. Argmin via
// index-in-mantissa fminf; zq gathered from the LDS bf16 frags (expand to
// fp32); loss from the distance surrogate (d^2 = ||z||^2 + 2*score).
// MFMA 16x16x32 bf16: A[m=lane&15][k=quad*8+j], B[k=quad*8+j][n=lane&15],
// D: col(n)=lane&15, row(m)=quad*4+reg.
// ---------------------------------------------------------------------------
__global__ __launch_bounds__(256, 2) void vq_fused_kernel(
    const float* __restrict__ ze, const float* __restrict__ cb,
    float* __restrict__ out_idx, float* __restrict__ zq,
    int* __restrict__ counts, float* __restrict__ lossAcc)
{
    __shared__ int4  bfr[4096];     // 64 KiB: B frags [chunk32][h2][lane64]
    __shared__ float norm_s[KCB];   // 2 KiB row norms
    __shared__ int   idx_s[WPT];    // 1 KiB per-window argmin
    __shared__ int   hist_s[KCB];   // 2 KiB histogram
    __shared__ float lpart[4];

    const int t    = threadIdx.x;
    const int lane = t & 63;
    const int wv   = t >> 6;
    const int q    = lane >> 4;
    const int l15  = lane & 15;
    const long blk = blockIdx.x;

    hist_s[t] = 0; hist_s[t + 256] = 0;

    // ---- codebook row norms (global reads, L2-hot)
    {
        const float4* c4 = (const float4*)cb;
        for (int rr = t; rr < KCB; rr += 256) {
            float s = 0.f;
#pragma unroll
            for (int i = 0; i < 16; ++i) {
                float4 v = c4[rr * 16 + i];
                s += v.x * v.x + v.y * v.y + v.z * v.z + v.w * v.w;
            }
            norm_s[rr] = s;
        }
    }

    // ---- stage ALL 512 codes as B fragments (once per block)
#pragma unroll
    for (int i = 0; i < 16; ++i) {
        int f = i * 256 + t;
        int L = f & 63, rest = f >> 6, h = rest & 1, c = rest >> 1;  // c=0..31
        int n = c * 16 + (L & 15);
        int k = h * 32 + (L >> 4) * 8;
        const float4* s4 = (const float4*)(cb + n * DIM + k);
        bfr[(c * 2 + h) * 64 + L] = pack8(s4[0], s4[1]);
    }
    __syncthreads();

    const float4* z4b = (const float4*)ze;
    float4*       zq4 = (float4*)zq;
    float lsum = 0.f;

    // ---- preload tile 0's A (raw fp32) into registers
    float4 abuf[16];
    {
        const float4* z4 = z4b + blk * TPB * WPT * 16;
#pragma unroll
        for (int tt = 0; tt < 4; ++tt)
#pragma unroll
            for (int h = 0; h < 2; ++h)
#pragma unroll
                for (int i = 0; i < 2; ++i) {
                    int m = wv * 64 + tt * 16 + l15;
                    abuf[tt * 4 + h * 2 + i] = z4[m * 16 + h * 8 + q * 2 + i];
                }
    }

#pragma unroll
    for (int tl = 0; tl < TPB; ++tl) {
        const long g = blk * TPB + tl;

        // prefetch next tile's A while this tile computes
        float4 pre[16];
        if (tl < TPB - 1) {
            const float4* z4 = z4b + (g + 1) * WPT * 16;
#pragma unroll
            for (int tt = 0; tt < 4; ++tt)
#pragma unroll
                for (int h = 0; h < 2; ++h)
#pragma unroll
                    for (int i = 0; i < 2; ++i) {
                        int m = wv * 64 + tt * 16 + l15;
                        pre[tt * 4 + h * 2 + i] = z4[m * 16 + h * 8 + q * 2 + i];
                    }
        }

        // pack current A to bf16 frags + window norms
        bf16x8 afrag[4][2];
        float  znorm[4];
#pragma unroll
        for (int tt = 0; tt < 4; ++tt) {
            float part = 0.f;
#pragma unroll
            for (int h = 0; h < 2; ++h) {
                float4 a0 = abuf[tt * 4 + h * 2], a1 = abuf[tt * 4 + h * 2 + 1];
                part += a0.x*a0.x + a0.y*a0.y + a0.z*a0.z + a0.w*a0.w
                      + a1.x*a1.x + a1.y*a1.y + a1.z*a1.z + a1.w*a1.w;
                afrag[tt][h] = __builtin_bit_cast(bf16x8, pack8(a0, a1));
            }
            part += __shfl_xor(part, 16, 64);
            part += __shfl_xor(part, 32, 64);
            znorm[tt] = part;
        }

        float best[4][4];
#pragma unroll
        for (int tt = 0; tt < 4; ++tt)
#pragma unroll
            for (int r = 0; r < 4; ++r) best[tt][r] = __uint_as_float(0x7e000000u);

        // ---- MFMA scan over all 512 codes
        for (int c = 0; c < 32; ++c) {
            bf16x8 b0 = __builtin_bit_cast(bf16x8, bfr[(c * 2 + 0) * 64 + lane]);
            bf16x8 b1 = __builtin_bit_cast(bf16x8, bfr[(c * 2 + 1) * 64 + lane]);
            int   n   = c * 16 + l15;
            float nrm = norm_s[n];
#pragma unroll
            for (int tt = 0; tt < 4; ++tt) {
                f32x4 acc = {0.f, 0.f, 0.f, 0.f};
                acc = __builtin_amdgcn_mfma_f32_16x16x32_bf16(afrag[tt][0], b0, acc, 0, 0, 0);
                acc = __builtin_amdgcn_mfma_f32_16x16x32_bf16(afrag[tt][1], b1, acc, 0, 0, 0);
#pragma unroll
                for (int r = 0; r < 4; ++r) {
                    float sc = fmaf(nrm, 0.5f, -acc[r]);   // 0.5||c||^2 - <z,c>
                    unsigned bb = (__float_as_uint(sc) & ~511u) | (unsigned)n;
                    best[tt][r] = fminf(best[tt][r], __uint_as_float(bb));
                }
            }
        }

        // ---- min across the 16 lanes of each quad (n-direction)
#pragma unroll
        for (int tt = 0; tt < 4; ++tt)
#pragma unroll
            for (int r = 0; r < 4; ++r) {
                float v = best[tt][r];
                v = fminf(v, __shfl_xor(v, 1, 64));
                v = fminf(v, __shfl_xor(v, 2, 64));
                v = fminf(v, __shfl_xor(v, 4, 64));
                v = fminf(v, __shfl_xor(v, 8, 64));
                best[tt][r] = v;
            }

        // owner lanes (l15 == q*4+r) record idx + loss surrogate
        {
            int  r_act = l15 - q * 4;
            bool act   = (r_act >= 0) && (r_act < 4);
#pragma unroll
            for (int tt = 0; tt < 4; ++tt) {
                if (act) {
                    unsigned bb = __float_as_uint(best[tt][r_act]);
                    int   n  = (int)(bb & 511u);
                    float sc = __uint_as_float(bb & ~511u);
                    lsum += fmaf(2.f, sc, znorm[tt]);      // d^2
                    idx_s[wv * 64 + tt * 16 + l15] = n;
                }
            }
        }
        __syncthreads();

        // coalesced index write + local histogram
        out_idx[g * WPT + t] = (float)idx_s[t];
        atomicAdd(&hist_s[idx_s[t]], 1);

        // ---- zq gather straight from LDS frags (bf16 -> fp32)
        {
            const long zb = g * WPT * 16;   // float4 units
#pragma unroll
            for (int it = 0; it < 16; ++it) {
                int w_loc = it * 16 + (t >> 4);
                int j  = t & 15;            // float4 index in window (k=4j..4j+3)
                int n  = idx_s[w_loc];
                int c  = n >> 4, ln = n & 15;
                int h  = j >> 3;
                int q2 = (j >> 1) & 3;
                int4 v = bfr[(c * 2 + h) * 64 + q2 * 16 + ln];
                int a  = (j & 1) ? v.z : v.x;
                int b  = (j & 1) ? v.w : v.y;
                float4 o;
                o.x = __uint_as_float((unsigned)a << 16);
                o.y = __uint_as_float((unsigned)a & 0xffff0000u);
                o.z = __uint_as_float((unsigned)b << 16);
                o.w = __uint_as_float((unsigned)b & 0xffff0000u);
                zq4[zb + (long)w_loc * 16 + j] = o;
            }
        }
        __syncthreads();   // idx_s reused next tile

        if (tl < TPB - 1) {
#pragma unroll
            for (int i = 0; i < 16; ++i) abuf[i] = pre[i];
        }
    }

    // ---- loss reduce + histogram flush
#pragma unroll
    for (int off = 32; off; off >>= 1) lsum += __shfl_down(lsum, off, 64);
    if (lane == 0) lpart[wv] = lsum;
    __syncthreads();
    if (t == 0) atomicAdd(lossAcc, lpart[0] + lpart[1] + lpart[2] + lpart[3]);

    int h0 = hist_s[t], h1 = hist_s[t + 256];
    if (h0) atomicAdd(&counts[t], h0);
    if (h1) atomicAdd(&counts[t + 256], h1);
}

// ---------------------------------------------------------------------------
// Finalize: entropy from counts + loss scalars
// ---------------------------------------------------------------------------
__global__ __launch_bounds__(512) void vq_finalize_kernel(
    const int* __restrict__ counts, const float* __restrict__ lossAcc,
    float* __restrict__ outs)
{
    __shared__ float partial[8];
    const int t = threadIdx.x;

    float p = (float)counts[t] * 0.1f;
    float term = p * logf(p + 1e-10f);
#pragma unroll
    for (int off = 32; off; off >>= 1) term += __shfl_down(term, off, 64);
    if ((t & 63) == 0) partial[t >> 6] = term;
    __syncthreads();
    if (t == 0) {
        float e = 0.f;
#pragma unroll
        for (int i = 0; i < 8; ++i) e += partial[i];
        float loss = lossAcc[0] / (float)ZQN;
        outs[0] = loss;
        outs[1] = loss;
        outs[2] = e;
    }
}

extern "C" void kernel_launch(void* const* d_in, const int* in_sizes, int n_in,
                              void* d_out, int out_size, void* d_ws, size_t ws_size,
                              hipStream_t stream) {
    const float* ze = (const float*)d_in[0];   // [16384, 2048] fp32
    const float* cb = (const float*)d_in[1];   // [512, 64] fp32
    float* out = (float*)d_out;

    // d_out layout: [idx: NWIN | zq: ZQN | vq_e | vq_commit | entropy]
    float* out_idx = out;
    float* out_zq  = out + NWIN;
    float* out_scl = out + NWIN + (long)ZQN;

    int*   counts  = (int*)d_ws;
    float* lossAcc = (float*)((char*)d_ws + KCB * sizeof(int));
    hipMemsetAsync(d_ws, 0, KCB * sizeof(int) + sizeof(float), stream);

    vq_fused_kernel<<<NBLK, 256, 0, stream>>>(ze, cb, out_idx, out_zq, counts, lossAcc);
    vq_finalize_kernel<<<1, KCB, 0, stream>>>(counts, lossAcc, out_scl);
}

// Round 5
// 278.314 us; speedup vs baseline: 4.1446x; 1.0249x over previous
//
#include <hip/hip_runtime.h>
#include <math.h>

// Problem constants
#define DIM 64
#define KCB 512
#define NWIN 524288              // 16384 * 32 windows
#define ZQN (NWIN * DIM)         // 33554432
#define WPT 512                  // windows per tile (== threads per block)
#define TPB 2                    // tiles per block
#define NBLK (NWIN / (WPT * TPB))  // 512 blocks = 2 per CU

typedef __attribute__((ext_vector_type(8))) short bf16x8;  // 8 bf16 = 4 VGPRs
typedef __attribute__((ext_vector_type(4))) float f32x4;

__device__ __forceinline__ unsigned bfbits(float f) { return __float_as_uint(f) >> 16; }

// pack 8 fp32 -> 8 bf16 (truncation; tolerance budget is enormous)
__device__ __forceinline__ int4 pack8(float4 a, float4 b) {
    int4 r;
    r.x = (int)(bfbits(a.x) | (__float_as_uint(a.y) & 0xffff0000u));
    r.y = (int)(bfbits(a.z) | (__float_as_uint(a.w) & 0xffff0000u));
    r.z = (int)(bfbits(b.x) | (__float_as_uint(b.y) & 0xffff0000u));
    r.w = (int)(bfbits(b.z) | (__float_as_uint(b.w) & 0xffff0000u));
    return r;
}

// ---------------------------------------------------------------------------
// Fused VQ kernel, v3:
//  - all 512 codes staged once as bf16 MFMA B-frags (64 KiB LDS)
//  - score = 0.5||c||^2 - <z,c> computed ENTIRELY in MFMA: A holds -z,
//    C-operand initialized to halved norm (broadcast, shared across tt)
//  - epilogue per entry: v_and_or_b32 (pack idx into low 9 mantissa bits)
//    + v_min3_f32 (c-loop unrolled x2)
//  - 512-thread blocks, launch_bounds(512,4) -> 16 waves/CU (2 blocks/CU)
//  - next tile's A global loads issued before the gather phase (no extra regs)
// MFMA 16x16x32 bf16: A[m=lane&15][k=quad*8+j], B[k=quad*8+j][n=lane&15],
// D: col(n)=lane&15, row(m)=quad*4+reg.
// ---------------------------------------------------------------------------
__global__ __launch_bounds__(512, 4) void vq_fused_kernel(
    const float* __restrict__ ze, const float* __restrict__ cb,
    float* __restrict__ out_idx, float* __restrict__ zq,
    int* __restrict__ counts, float* __restrict__ lossAcc)
{
    __shared__ int4  bfr[4096];     // 64 KiB: B frags [chunk32][h2][lane64]
    __shared__ float norm_s[KCB];   // 2 KiB HALVED row norms (0.5*||c||^2)
    __shared__ int   idx_s[WPT];    // 2 KiB per-window argmin
    __shared__ int   hist_s[KCB];   // 2 KiB histogram
    __shared__ float lpart[8];

    const int t    = threadIdx.x;   // 0..511
    const int lane = t & 63;
    const int wv   = t >> 6;        // wave 0..7
    const int q    = lane >> 4;
    const int l15  = lane & 15;
    const long blk = blockIdx.x;

    hist_s[t] = 0;

    // ---- halved codebook row norms (one row per thread)
    {
        const float4* c4 = (const float4*)cb;
        float s = 0.f;
#pragma unroll
        for (int i = 0; i < 16; ++i) {
            float4 v = c4[t * 16 + i];
            s += v.x * v.x + v.y * v.y + v.z * v.z + v.w * v.w;
        }
        norm_s[t] = 0.5f * s;
    }

    // ---- stage ALL 512 codes as B fragments (once per block)
#pragma unroll
    for (int i = 0; i < 8; ++i) {
        int f = i * 512 + t;
        int L = f & 63, rest = f >> 6, h = rest & 1, c = rest >> 1;  // c=0..31
        int n = c * 16 + (L & 15);
        int k = h * 32 + (L >> 4) * 8;
        const float4* s4 = (const float4*)(cb + n * DIM + k);
        bfr[(c * 2 + h) * 64 + L] = pack8(s4[0], s4[1]);
    }

    const float4* z4b = (const float4*)ze;
    float4*       zq4 = (float4*)zq;
    float lsum = 0.f;

    // ---- issue tile 0's A loads (global, no LDS dependency)
    float4 abuf[16];
    {
        const float4* z4 = z4b + blk * TPB * WPT * 16;
        const int m = wv * 64 + l15;   // + tt*16 below
#pragma unroll
        for (int tt = 0; tt < 4; ++tt)
#pragma unroll
            for (int h = 0; h < 2; ++h)
#pragma unroll
                for (int i = 0; i < 2; ++i)
                    abuf[tt * 4 + h * 2 + i] = z4[(m + tt * 16) * 16 + h * 8 + q * 2 + i];
    }
    __syncthreads();   // bfr + norms visible

#pragma unroll
    for (int tl = 0; tl < TPB; ++tl) {
        const long g = blk * TPB + tl;

        // ---- pack current A to NEGATED bf16 frags + window norms
        bf16x8 afrag[4][2];
        float  znorm[4];
#pragma unroll
        for (int tt = 0; tt < 4; ++tt) {
            float part = 0.f;
#pragma unroll
            for (int h = 0; h < 2; ++h) {
                float4 a0 = abuf[tt * 4 + h * 2], a1 = abuf[tt * 4 + h * 2 + 1];
                part += a0.x*a0.x + a0.y*a0.y + a0.z*a0.z + a0.w*a0.w
                      + a1.x*a1.x + a1.y*a1.y + a1.z*a1.z + a1.w*a1.w;
                int4 p = pack8(a0, a1);
                p.x ^= 0x80008000; p.y ^= 0x80008000;   // negate both bf16 halves
                p.z ^= 0x80008000; p.w ^= 0x80008000;
                afrag[tt][h] = __builtin_bit_cast(bf16x8, p);
            }
            part += __shfl_xor(part, 16, 64);
            part += __shfl_xor(part, 32, 64);
            znorm[tt] = part;
        }

        float best[4][4];
#pragma unroll
        for (int tt = 0; tt < 4; ++tt)
#pragma unroll
            for (int r = 0; r < 4; ++r) best[tt][r] = __uint_as_float(0x7e000000u);

        // ---- MFMA scan over 512 codes, 2 code-chunks per iteration
        for (int cp = 0; cp < 16; ++cp) {
            f32x4 e0[4], e1[4];
            {   // chunk c = 2*cp
                const int c = 2 * cp;
                bf16x8 b0 = __builtin_bit_cast(bf16x8, bfr[(c * 2 + 0) * 64 + lane]);
                bf16x8 b1 = __builtin_bit_cast(bf16x8, bfr[(c * 2 + 1) * 64 + lane]);
                float nh = norm_s[c * 16 + l15];
                f32x4 nrm4 = {nh, nh, nh, nh};
#pragma unroll
                for (int tt = 0; tt < 4; ++tt) {
                    e0[tt] = __builtin_amdgcn_mfma_f32_16x16x32_bf16(afrag[tt][0], b0, nrm4, 0, 0, 0);
                    e0[tt] = __builtin_amdgcn_mfma_f32_16x16x32_bf16(afrag[tt][1], b1, e0[tt], 0, 0, 0);
                }
            }
            {   // chunk c = 2*cp+1
                const int c = 2 * cp + 1;
                bf16x8 b0 = __builtin_bit_cast(bf16x8, bfr[(c * 2 + 0) * 64 + lane]);
                bf16x8 b1 = __builtin_bit_cast(bf16x8, bfr[(c * 2 + 1) * 64 + lane]);
                float nh = norm_s[c * 16 + l15];
                f32x4 nrm4 = {nh, nh, nh, nh};
#pragma unroll
                for (int tt = 0; tt < 4; ++tt) {
                    e1[tt] = __builtin_amdgcn_mfma_f32_16x16x32_bf16(afrag[tt][0], b0, nrm4, 0, 0, 0);
                    e1[tt] = __builtin_amdgcn_mfma_f32_16x16x32_bf16(afrag[tt][1], b1, e1[tt], 0, 0, 0);
                }
            }
            const unsigned n0 = (unsigned)(2 * cp) * 16 + (unsigned)l15;
            const unsigned n1 = n0 + 16;
#pragma unroll
            for (int tt = 0; tt < 4; ++tt)
#pragma unroll
                for (int r = 0; r < 4; ++r) {
                    float p0 = __uint_as_float((__float_as_uint(e0[tt][r]) & ~511u) | n0);
                    float p1 = __uint_as_float((__float_as_uint(e1[tt][r]) & ~511u) | n1);
                    best[tt][r] = fminf(fminf(best[tt][r], p0), p1);   // -> v_min3_f32
                }
        }

        // ---- min across the 16 lanes of each quad (n-direction)
#pragma unroll
        for (int tt = 0; tt < 4; ++tt)
#pragma unroll
            for (int r = 0; r < 4; ++r) {
                float v = best[tt][r];
                v = fminf(v, __shfl_xor(v, 1, 64));
                v = fminf(v, __shfl_xor(v, 2, 64));
                v = fminf(v, __shfl_xor(v, 4, 64));
                v = fminf(v, __shfl_xor(v, 8, 64));
                best[tt][r] = v;
            }

        // owner lanes (l15 == q*4+r) record idx + loss surrogate
        {
            int  r_act = l15 - q * 4;
            bool act   = (r_act >= 0) && (r_act < 4);
#pragma unroll
            for (int tt = 0; tt < 4; ++tt) {
                if (act) {
                    unsigned bb = __float_as_uint(best[tt][r_act]);
                    int   n  = (int)(bb & 511u);
                    float sc = __uint_as_float(bb & ~511u);
                    lsum += fmaf(2.f, sc, znorm[tt]);      // d^2 = ||z||^2 + 2*score
                    idx_s[wv * 64 + tt * 16 + l15] = n;
                }
            }
        }

        // ---- issue NEXT tile's A loads now; they drain across barrier+gather
        if (tl < TPB - 1) {
            const float4* z4 = z4b + (g + 1) * WPT * 16;
            const int m = wv * 64 + l15;
#pragma unroll
            for (int tt = 0; tt < 4; ++tt)
#pragma unroll
                for (int h = 0; h < 2; ++h)
#pragma unroll
                    for (int i = 0; i < 2; ++i)
                        abuf[tt * 4 + h * 2 + i] = z4[(m + tt * 16) * 16 + h * 8 + q * 2 + i];
        }
        __syncthreads();   // idx_s complete

        // coalesced index write + local histogram
        out_idx[g * WPT + t] = (float)idx_s[t];
        atomicAdd(&hist_s[idx_s[t]], 1);

        // ---- zq gather straight from LDS frags (bf16 -> fp32)
        {
            const long zb = g * WPT * 16;   // float4 units
#pragma unroll
            for (int it = 0; it < 16; ++it) {
                int w_loc = it * 32 + (t >> 4);
                int j  = t & 15;            // float4 index in window
                int n  = idx_s[w_loc];
                int c  = n >> 4, ln = n & 15;
                int h  = j >> 3;
                int q2 = (j >> 1) & 3;
                int4 v = bfr[(c * 2 + h) * 64 + q2 * 16 + ln];
                int a  = (j & 1) ? v.z : v.x;
                int b  = (j & 1) ? v.w : v.y;
                float4 o;
                o.x = __uint_as_float((unsigned)a << 16);
                o.y = __uint_as_float((unsigned)a & 0xffff0000u);
                o.z = __uint_as_float((unsigned)b << 16);
                o.w = __uint_as_float((unsigned)b & 0xffff0000u);
                zq4[zb + (long)w_loc * 16 + j] = o;
            }
        }
        __syncthreads();   // idx_s reused next tile
    }

    // ---- loss reduce + histogram flush
#pragma unroll
    for (int off = 32; off; off >>= 1) lsum += __shfl_down(lsum, off, 64);
    if (lane == 0) lpart[wv] = lsum;
    __syncthreads();
    if (t == 0) {
        float s = 0.f;
#pragma unroll
        for (int i = 0; i < 8; ++i) s += lpart[i];
        atomicAdd(lossAcc, s);
    }
    int h0 = hist_s[t];
    if (h0) atomicAdd(&counts[t], h0);
}

// ---------------------------------------------------------------------------
// Finalize: entropy from counts + loss scalars
// ---------------------------------------------------------------------------
__global__ __launch_bounds__(512) void vq_finalize_kernel(
    const int* __restrict__ counts, const float* __restrict__ lossAcc,
    float* __restrict__ outs)
{
    __shared__ float partial[8];
    const int t = threadIdx.x;

    float p = (float)counts[t] * 0.1f;
    float term = p * logf(p + 1e-10f);
#pragma unroll
    for (int off = 32; off; off >>= 1) term += __shfl_down(term, off, 64);
    if ((t & 63) == 0) partial[t >> 6] = term;
    __syncthreads();
    if (t == 0) {
        float e = 0.f;
#pragma unroll
        for (int i = 0; i < 8; ++i) e += partial[i];
        float loss = lossAcc[0] / (float)ZQN;
        outs[0] = loss;
        outs[1] = loss;
        outs[2] = e;
    }
}

extern "C" void kernel_launch(void* const* d_in, const int* in_sizes, int n_in,
                              void* d_out, int out_size, void* d_ws, size_t ws_size,
                              hipStream_t stream) {
    const float* ze = (const float*)d_in[0];   // [16384, 2048] fp32
    const float* cb = (const float*)d_in[1];   // [512, 64] fp32
    float* out = (float*)d_out;

    // d_out layout: [idx: NWIN | zq: ZQN | vq_e | vq_commit | entropy]
    float* out_idx = out;
    float* out_zq  = out + NWIN;
    float* out_scl = out + NWIN + (long)ZQN;

    int*   counts  = (int*)d_ws;
    float* lossAcc = (float*)((char*)d_ws + KCB * sizeof(int));
    hipMemsetAsync(d_ws, 0, KCB * sizeof(int) + sizeof(float), stream);

    vq_fused_kernel<<<NBLK, 512, 0, stream>>>(ze, cb, out_idx, out_zq, counts, lossAcc);
    vq_finalize_kernel<<<1, KCB, 0, stream>>>(counts, lossAcc, out_scl);
}